// Round 2
// baseline (1341.426 us; speedup 1.0000x reference)
//
#include <hip/hip_runtime.h>
#include <hip/hip_bf16.h>
#include <math.h>

#define BB 256
#define NAA 64
#define NTOK 65
#define DD 512
#define HH 16
#define HDD 32
#define NGEFF 4          // bond values 0..15 -> bits 4,5 of (bond-1) always 0; table row 0 is 0
#define MAXP 50

// ---------------------------------------------------------------- atom embed
__global__ __launch_bounds__(256)
void k_atom_embed(const int* __restrict__ atom_fea,          // [B][7][64]
                  const float* __restrict__ atom_tables,     // [6][100][512]
                  const float* __restrict__ ga_means,        // [512]
                  const float* __restrict__ ga_stds,
                  const float* __restrict__ ga_mul,
                  const float* __restrict__ ga_bias,
                  const float* __restrict__ graph_token,     // [512]
                  float* __restrict__ x)                     // [B][65][512]
{
    int n = blockIdx.x;   // 0..64
    int b = blockIdx.y;
    int tid = threadIdx.x;
    float* xp = x + ((size_t)b * NTOK + n) * DD;
    if (n == 0) {
        for (int d = tid; d < DD; d += 256) xp[d] = graph_token[d];
        return;
    }
    int a = n - 1;
    int fea[6];
#pragma unroll
    for (int i = 0; i < 6; ++i) fea[i] = atom_fea[((b * 7) + i) * NAA + a];
    int ci = atom_fea[((b * 7) + 6) * NAA + a];
    float cont = (float)ci;
    float g = ga_mul[0] * cont + ga_bias[0];
    const float Ac = 2.5066268f;    // sqrt(2*3.14159)
    for (int d = tid; d < DD; d += 256) {
        float val = 0.f;
        if (ci != 0) {
            float sd = fabsf(ga_stds[d]) + 1e-5f;
            float t = (g - ga_means[d]) / sd;
            val = expf(-0.5f * t * t) / (Ac * sd);
        }
#pragma unroll
        for (int i = 0; i < 6; ++i)
            val += atom_tables[((i * 100) + fea[i]) * DD + d];
        xp[d] = val;
    }
}

// ---------------------------------------------------------------- edge bias
__global__ __launch_bounds__(256)
void k_edge_bias(const int* __restrict__ bond_adj,           // [B][64][64]
                 const float* __restrict__ dist_adj,         // [B][64][64]
                 const float* __restrict__ edge_tables,      // [6][51][16]
                 const float* __restrict__ gb_means,         // [16]
                 const float* __restrict__ gb_stds,
                 const float* __restrict__ gb_mul,
                 const float* __restrict__ gb_bias,
                 const float* __restrict__ egt,              // [16]
                 float* __restrict__ comb,                   // [B][4096][16] scratch
                 float* __restrict__ biasb)                  // [B][16][65][65]
{
    int b = blockIdx.x;
    int tid = threadIdx.x;
    __shared__ float s_j[4096];
    __shared__ float s_jn[4096];
    __shared__ unsigned long long s_brow[64];
    __shared__ unsigned char s_idx[4][4096];

    const int* badj = bond_adj + (size_t)b * 4096;

    // phase A: gaussian init of comb
    float mean[16], istd[16], coef[16];
    const float Ac = 2.5066268f;
#pragma unroll
    for (int hh = 0; hh < 16; ++hh) {
        float sd = fabsf(gb_stds[hh]) + 1e-5f;
        mean[hh] = gb_means[hh];
        istd[hh] = 1.f / sd;
        coef[hh] = 1.f / (Ac * sd);
    }
    float gm = gb_mul[0], gbi = gb_bias[0];
    for (int p = tid; p < 4096; p += 256) {
        float dist = dist_adj[(size_t)b * 4096 + p];
        float g = gm * dist + gbi;
        float* cp = comb + ((size_t)b * 4096 + p) * 16;
        if (dist != 0.f) {
#pragma unroll
            for (int hh = 0; hh < 16; ++hh) {
                float t = (g - mean[hh]) * istd[hh];
                cp[hh] = expf(-0.5f * t * t) * coef[hh];
            }
        } else {
#pragma unroll
            for (int hh = 0; hh < 16; ++hh) cp[hh] = 0.f;
        }
    }

    // phase B: per bond-type bit-plane, path-count powers + table accumulation
    for (int t = 0; t < NGEFF; ++t) {
        for (int q = tid; q < 4096; q += 256) {
            int c = q & 63;
            int bd = badj[q];
            int bit = (bd > 0) ? ((bd - 1) >> t) & 1 : 0;
            unsigned long long m = __ballot(bit != 0);
            if (c == 0) s_brow[q >> 6] = m;
            s_j[q] = (float)bit;
            s_idx[0][q] = (unsigned char)bit;
        }
        __syncthreads();
        float* cur = s_j;
        float* nxt = s_jn;
        for (int hop = 1; hop < 4; ++hop) {
            int r = tid >> 2;
            int c0 = (tid & 3) << 4;
            float acc[16];
#pragma unroll
            for (int c = 0; c < 16; ++c) acc[c] = 0.f;
            for (int k = 0; k < 64; ++k) {
                float jv = cur[r * 64 + k];
                if (jv != 0.f) {
                    unsigned int rs = (unsigned int)(s_brow[k] >> c0);
#pragma unroll
                    for (int c = 0; c < 16; ++c)
                        acc[c] += ((rs >> c) & 1u) ? jv : 0.f;
                }
            }
#pragma unroll
            for (int c = 0; c < 16; ++c) {
                nxt[r * 64 + c0 + c] = acc[c];
                int iv = (int)acc[c];
                if (iv > MAXP) iv = MAXP;
                s_idx[hop][r * 64 + c0 + c] = (unsigned char)iv;
            }
            __syncthreads();
            float* tmp = cur; cur = nxt; nxt = tmp;
        }
        // accumulate table lookups into comb (same-thread ownership as phase A)
        for (int p = tid; p < 4096; p += 256) {
            float* cp = comb + ((size_t)b * 4096 + p) * 16;
            float v[16];
            float4 v0 = *(const float4*)&cp[0];
            float4 v1 = *(const float4*)&cp[4];
            float4 v2 = *(const float4*)&cp[8];
            float4 v3 = *(const float4*)&cp[12];
            v[0]=v0.x; v[1]=v0.y; v[2]=v0.z; v[3]=v0.w;
            v[4]=v1.x; v[5]=v1.y; v[6]=v1.z; v[7]=v1.w;
            v[8]=v2.x; v[9]=v2.y; v[10]=v2.z; v[11]=v2.w;
            v[12]=v3.x; v[13]=v3.y; v[14]=v3.z; v[15]=v3.w;
#pragma unroll
            for (int hop = 0; hop < 4; ++hop) {
                int idx = s_idx[hop][p];
                const float* et = edge_tables + ((t * 51) + idx) * 16;
#pragma unroll
                for (int hh = 0; hh < 16; ++hh) v[hh] += et[hh];
            }
            v0 = make_float4(v[0], v[1], v[2], v[3]);
            v1 = make_float4(v[4], v[5], v[6], v[7]);
            v2 = make_float4(v[8], v[9], v[10], v[11]);
            v3 = make_float4(v[12], v[13], v[14], v[15]);
            *(float4*)&cp[0] = v0; *(float4*)&cp[4] = v1;
            *(float4*)&cp[8] = v2; *(float4*)&cp[12] = v3;
        }
        __syncthreads();
    }

    // phase C: emit bias[b][h][65][65] with mask + graph-token row/col
    float egtv[16];
#pragma unroll
    for (int hh = 0; hh < 16; ++hh) egtv[hh] = egt[hh];
    float* bb = biasb + (size_t)b * HH * NTOK * NTOK;
    for (int i = tid; i < HH * NTOK; i += 256) {
        int hh = i / NTOK, j = i - hh * NTOK;
        bb[(hh * NTOK + 0) * NTOK + j] = egtv[hh];
        bb[(hh * NTOK + j) * NTOK + 0] = egtv[hh];
    }
    for (int p = tid; p < 4096; p += 256) {
        int a1 = p >> 6, a2 = p & 63;
        float m = (badj[p] != 0) ? 0.f : -INFINITY;
        const float* cp = comb + ((size_t)b * 4096 + p) * 16;
#pragma unroll
        for (int hh = 0; hh < 16; ++hh)
            bb[(hh * NTOK + (a1 + 1)) * NTOK + (a2 + 1)] = cp[hh] + m;
    }
}

// ---------------------------------------------------------------- GEMM: C = A * W^T + bias
// A [M][K] f32, W [Nc][K] f32, bias [Nc] f32, C [M][Nc] f32
#define GBM 128
#define GBN 128
#define GBK 16
__global__ __launch_bounds__(256)
void k_gemm(const float* __restrict__ A, const float* __restrict__ W,
            const float* __restrict__ bias, float* __restrict__ C,
            int M, int Nc, int K)
{
    __shared__ float sA[GBK][GBM + 4];
    __shared__ float sB[GBK][GBN + 4];
    int tid = threadIdx.x;
    int row0 = blockIdx.x * GBM, col0 = blockIdx.y * GBN;
    int tx = tid & 15, ty = tid >> 4;
    float acc[8][8];
#pragma unroll
    for (int i = 0; i < 8; ++i)
#pragma unroll
        for (int j = 0; j < 8; ++j) acc[i][j] = 0.f;

    for (int kb = 0; kb < K; kb += GBK) {
        for (int q = tid; q < 512; q += 256) {
            int r = q >> 2, kk = (q & 3) << 2;
            float4 v = *(const float4*)&A[(size_t)(row0 + r) * K + kb + kk];
            sA[kk + 0][r] = v.x; sA[kk + 1][r] = v.y;
            sA[kk + 2][r] = v.z; sA[kk + 3][r] = v.w;
        }
        for (int q = tid; q < 512; q += 256) {
            int c = q >> 2, kk = (q & 3) << 2;
            float4 v = *(const float4*)&W[(size_t)(col0 + c) * K + kb + kk];
            sB[kk + 0][c] = v.x; sB[kk + 1][c] = v.y;
            sB[kk + 2][c] = v.z; sB[kk + 3][c] = v.w;
        }
        __syncthreads();
#pragma unroll
        for (int k = 0; k < GBK; ++k) {
            float a[8], bv[8];
            *(float4*)&a[0] = *(const float4*)&sA[k][ty * 8];
            *(float4*)&a[4] = *(const float4*)&sA[k][ty * 8 + 4];
            *(float4*)&bv[0] = *(const float4*)&sB[k][tx * 8];
            *(float4*)&bv[4] = *(const float4*)&sB[k][tx * 8 + 4];
#pragma unroll
            for (int i = 0; i < 8; ++i)
#pragma unroll
                for (int j = 0; j < 8; ++j) acc[i][j] += a[i] * bv[j];
        }
        __syncthreads();
    }
    float bv[8];
#pragma unroll
    for (int j = 0; j < 8; ++j) bv[j] = bias[col0 + tx * 8 + j];
#pragma unroll
    for (int i = 0; i < 8; ++i) {
        float* cp = &C[(size_t)(row0 + ty * 8 + i) * Nc + col0 + tx * 8];
#pragma unroll
        for (int j = 0; j < 8; ++j) cp[j] = acc[i][j] + bv[j];
    }
}

// ---------------------------------------------------------------- attention
__global__ __launch_bounds__(256)
void k_attn(const float* __restrict__ qkv,   // [B][65][1536]
            const float* __restrict__ biasb, // [B][16][65][65]
            float* __restrict__ out)         // [B][65][512]
{
    int h = blockIdx.x, b = blockIdx.y;
    int tid = threadIdx.x;
    __shared__ float sq[NTOK * HDD];
    __shared__ float sk[NTOK * HDD];
    __shared__ float svT[HDD][NTOK + 3];   // transposed V
    __shared__ float sS[NTOK][NTOK + 3];   // scores (row stride 68 -> 16B aligned)

    const float* qb = qkv + (size_t)b * NTOK * (3 * DD) + h * HDD;
    for (int i = tid; i < NTOK * HDD; i += 256) {
        int n = i >> 5, d = i & 31;
        const float* row = qb + (size_t)n * (3 * DD);
        sq[i] = row[d];
        sk[i] = row[DD + d];
        svT[d][n] = row[2 * DD + d];
    }
    __syncthreads();

    const float scale = 0.17677669529663687f;   // 1/sqrt(32)
    const float* bp = biasb + (((size_t)b * HH + h) * NTOK) * NTOK;
    for (int e = tid; e < NTOK * NTOK; e += 256) {
        int i = e / NTOK, j = e - i * NTOK;
        const float* qr = &sq[i * HDD];
        const float* kr = &sk[j * HDD];
        float dot = 0.f;
#pragma unroll
        for (int d4 = 0; d4 < HDD; d4 += 4) {
            float4 qv = *(const float4*)&qr[d4];
            float4 kv = *(const float4*)&kr[d4];
            dot += qv.x * kv.x + qv.y * kv.y + qv.z * kv.z + qv.w * kv.w;
        }
        sS[i][j] = dot * scale + bp[i * NTOK + j];
    }
    __syncthreads();

    if (tid < NTOK) {
        float* r = sS[tid];
        float mx = -INFINITY;
        for (int j = 0; j < NTOK; ++j) mx = fmaxf(mx, r[j]);
        float s = 0.f;
        for (int j = 0; j < NTOK; ++j) { float p = expf(r[j] - mx); r[j] = p; s += p; }
        float inv = 1.f / s;
        for (int j = 0; j < NTOK; ++j) r[j] *= inv;
    }
    __syncthreads();

    float* ob = out + (size_t)b * NTOK * DD + h * HDD;
    for (int e = tid; e < NTOK * HDD; e += 256) {
        int n = e >> 5, d = e & 31;
        const float* pr = sS[n];
        const float* vr = &svT[d][0];
        float accv = 0.f;
#pragma unroll
        for (int j4 = 0; j4 < 64; j4 += 4) {
            float4 pv = *(const float4*)&pr[j4];
            float4 vv = *(const float4*)&vr[j4];
            accv += pv.x * vv.x + pv.y * vv.y + pv.z * vv.z + pv.w * vv.w;
        }
        accv += pr[64] * vr[64];
        ob[(size_t)n * DD + d] = accv;
    }
}

// ---------------------------------------------------------------- launch
extern "C" void kernel_launch(void* const* d_in, const int* in_sizes, int n_in,
                              void* d_out, int out_size, void* d_ws, size_t ws_size,
                              hipStream_t stream)
{
    (void)in_sizes; (void)n_in; (void)out_size; (void)ws_size;
    const int*   atom_fea    = (const int*)d_in[0];
    const int*   bond_adj    = (const int*)d_in[1];
    const float* dist_adj    = (const float*)d_in[2];
    const float* atom_tables = (const float*)d_in[3];
    const float* ga_means    = (const float*)d_in[4];
    const float* ga_stds     = (const float*)d_in[5];
    const float* ga_mul      = (const float*)d_in[6];
    const float* ga_bias     = (const float*)d_in[7];
    const float* graph_token = (const float*)d_in[8];
    const float* edge_tables = (const float*)d_in[9];
    const float* gb_means    = (const float*)d_in[10];
    const float* gb_stds     = (const float*)d_in[11];
    const float* gb_mul      = (const float*)d_in[12];
    const float* gb_bias     = (const float*)d_in[13];
    const float* egt         = (const float*)d_in[14];
    const float* in_proj_w   = (const float*)d_in[15];
    const float* in_proj_b   = (const float*)d_in[16];
    const float* out_proj_w  = (const float*)d_in[17];
    const float* out_proj_b  = (const float*)d_in[18];

    float* xbuf = (float*)d_ws;                               // [B][65][512]   34.1 MB
    float* qkv  = xbuf + (size_t)BB * NTOK * DD;              // [B][65][1536] 102.2 MB
    float* comb = qkv;                                        // [B][4096][16]  aliased (dead before qkv GEMM)
    float* biasb = qkv + (size_t)BB * NTOK * 3 * DD;          // [B][16][65][65] 69.2 MB

    k_atom_embed<<<dim3(NTOK, BB), 256, 0, stream>>>(atom_fea, atom_tables, ga_means,
                                                     ga_stds, ga_mul, ga_bias, graph_token, xbuf);
    k_edge_bias<<<dim3(BB), 256, 0, stream>>>(bond_adj, dist_adj, edge_tables, gb_means,
                                              gb_stds, gb_mul, gb_bias, egt, comb, biasb);
    k_gemm<<<dim3(130, 12), 256, 0, stream>>>(xbuf, in_proj_w, in_proj_b, qkv,
                                              BB * NTOK, 3 * DD, DD);
    k_attn<<<dim3(HH, BB), 256, 0, stream>>>(qkv, biasb, xbuf);
    k_gemm<<<dim3(130, 4), 256, 0, stream>>>(xbuf, out_proj_w, out_proj_b, (float*)d_out,
                                             BB * NTOK, DD, DD);
}

// Round 3
// 922.084 us; speedup vs baseline: 1.4548x; 1.4548x over previous
//
#include <hip/hip_runtime.h>
#include <hip/hip_bf16.h>
#include <math.h>

#define BB 256
#define NAA 64
#define NTOK 65
#define DD 512
#define HH 16
#define HDD 32
#define NGEFF 4          // bond values 0..15 -> bits 4,5 of (bond-1) always 0; table row 0 is 0
#define MAXP 50

// ---------------------------------------------------------------- atom embed
__global__ __launch_bounds__(256)
void k_atom_embed(const int* __restrict__ atom_fea,          // [B][7][64]
                  const float* __restrict__ atom_tables,     // [6][100][512]
                  const float* __restrict__ ga_means,        // [512]
                  const float* __restrict__ ga_stds,
                  const float* __restrict__ ga_mul,
                  const float* __restrict__ ga_bias,
                  const float* __restrict__ graph_token,     // [512]
                  float* __restrict__ x)                     // [B][65][512]
{
    int n = blockIdx.x;   // 0..64
    int b = blockIdx.y;
    int tid = threadIdx.x;
    float* xp = x + ((size_t)b * NTOK + n) * DD;
    if (n == 0) {
        for (int d = tid; d < DD; d += 256) xp[d] = graph_token[d];
        return;
    }
    int a = n - 1;
    int fea[6];
#pragma unroll
    for (int i = 0; i < 6; ++i) fea[i] = atom_fea[((b * 7) + i) * NAA + a];
    int ci = atom_fea[((b * 7) + 6) * NAA + a];
    float cont = (float)ci;
    float g = ga_mul[0] * cont + ga_bias[0];
    const float Ac = 2.5066268f;    // sqrt(2*3.14159)
    for (int d = tid; d < DD; d += 256) {
        float val = 0.f;
        if (ci != 0) {
            float sd = fabsf(ga_stds[d]) + 1e-5f;
            float t = (g - ga_means[d]) / sd;
            val = expf(-0.5f * t * t) / (Ac * sd);
        }
#pragma unroll
        for (int i = 0; i < 6; ++i)
            val += atom_tables[((i * 100) + fea[i]) * DD + d];
        xp[d] = val;
    }
}

// ---------------------------------------------------------------- edge bias (fully LDS-resident)
__global__ __launch_bounds__(1024)
void k_edge_bias(const int* __restrict__ bond_adj,           // [B][64][64]
                 const float* __restrict__ dist_adj,         // [B][64][64]
                 const float* __restrict__ edge_tables,      // [6][51][16]
                 const float* __restrict__ gb_means,         // [16]
                 const float* __restrict__ gb_stds,
                 const float* __restrict__ gb_mul,
                 const float* __restrict__ gb_bias,
                 const float* __restrict__ egt,              // [16]
                 float* __restrict__ biasb)                  // [B][16][65][65]
{
    int b = blockIdx.x;
    int tid = threadIdx.x;
    __shared__ float s_j[64 * 65];                 // 16.25 KB (stride 65 breaks bank aliasing)
    __shared__ float s_jn[64 * 65];                // 16.25 KB
    __shared__ unsigned long long s_brow[64];      // 0.5 KB
    __shared__ unsigned char s_idx[16][4096];      // 64 KB   [t*4+hop][p]
    __shared__ float s_et[4][51][17];              // 13.9 KB (padded rows)
    __shared__ int s_bond[4096];                   // 16 KB
    __shared__ float s_gmn[16], s_gis[16], s_gcf[16], s_egt[16];

    const int* badj = bond_adj + (size_t)b * 4096;
    const float Ac = 2.5066268f;

    for (int q = tid; q < 4096; q += 1024) s_bond[q] = badj[q];
    for (int q = tid; q < 4 * 51 * 16; q += 1024) {
        int t = q >> 4;                 // combined (t*51+idx)
        int hh = q & 15;
        s_et[t / 51][t % 51][hh] = edge_tables[q];
    }
    if (tid < 16) {
        float sd = fabsf(gb_stds[tid]) + 1e-5f;
        s_gmn[tid] = gb_means[tid];
        s_gis[tid] = 1.f / sd;
        s_gcf[tid] = 1.f / (Ac * sd);
        s_egt[tid] = egt[tid];
    }
    __syncthreads();

    // per bond-type bit-plane: build bits, 3 LDS matmuls, record clipped indices
    for (int t = 0; t < NGEFF; ++t) {
        for (int q = tid; q < 4096; q += 1024) {
            int bd = s_bond[q];
            int bit = (bd > 0) ? ((bd - 1) >> t) & 1 : 0;
            unsigned long long m = __ballot(bit != 0);
            if ((q & 63) == 0) s_brow[q >> 6] = m;
            s_j[(q >> 6) * 65 + (q & 63)] = (float)bit;
            s_idx[t * 4][q] = (unsigned char)bit;
        }
        __syncthreads();
        float* cur = s_j;
        float* nxt = s_jn;
        for (int hop = 1; hop < 4; ++hop) {
            int r = tid >> 4;              // 0..63
            int c0 = (tid & 15) << 2;      // 4 columns per thread
            float a0 = 0.f, a1 = 0.f, a2 = 0.f, a3 = 0.f;
            for (int k = 0; k < 64; ++k) {
                float jv = cur[r * 65 + k];
                unsigned int rs = (unsigned int)(s_brow[k] >> c0);
                a0 += (rs & 1u) ? jv : 0.f;
                a1 += (rs & 2u) ? jv : 0.f;
                a2 += (rs & 4u) ? jv : 0.f;
                a3 += (rs & 8u) ? jv : 0.f;
            }
            nxt[r * 65 + c0 + 0] = a0;
            nxt[r * 65 + c0 + 1] = a1;
            nxt[r * 65 + c0 + 2] = a2;
            nxt[r * 65 + c0 + 3] = a3;
            int p0 = r * 64 + c0;
            int i0 = (int)a0; if (i0 > MAXP) i0 = MAXP;
            int i1 = (int)a1; if (i1 > MAXP) i1 = MAXP;
            int i2 = (int)a2; if (i2 > MAXP) i2 = MAXP;
            int i3 = (int)a3; if (i3 > MAXP) i3 = MAXP;
            s_idx[t * 4 + hop][p0 + 0] = (unsigned char)i0;
            s_idx[t * 4 + hop][p0 + 1] = (unsigned char)i1;
            s_idx[t * 4 + hop][p0 + 2] = (unsigned char)i2;
            s_idx[t * 4 + hop][p0 + 3] = (unsigned char)i3;
            __syncthreads();
            float* tmp = cur; cur = nxt; nxt = tmp;
        }
    }

    // fused final pass: gaussian + 16 table lookups + mask -> biasb, plus token row/col
    float* bb = biasb + (size_t)b * HH * NTOK * NTOK;
    for (int i = tid; i < HH * NTOK; i += 1024) {
        int hh = i / NTOK, j = i - hh * NTOK;
        float e = s_egt[hh];
        bb[(hh * NTOK + 0) * NTOK + j] = e;
        bb[(hh * NTOK + j) * NTOK + 0] = e;
    }
    float gm = gb_mul[0], gbi = gb_bias[0];
    for (int p = tid; p < 4096; p += 1024) {
        int a1i = p >> 6, a2i = p & 63;
        float dist = dist_adj[(size_t)b * 4096 + p];
        float g = gm * dist + gbi;
        float mv = (s_bond[p] != 0) ? 0.f : -INFINITY;
        int ixs[16];
#pragma unroll
        for (int q = 0; q < 16; ++q) ixs[q] = s_idx[q][p];
#pragma unroll
        for (int hh = 0; hh < 16; ++hh) {
            float v = 0.f;
            if (dist != 0.f) {
                float tt = (g - s_gmn[hh]) * s_gis[hh];
                v = expf(-0.5f * tt * tt) * s_gcf[hh];
            }
#pragma unroll
            for (int q = 0; q < 16; ++q) v += s_et[q >> 2][ixs[q]][hh];
            bb[(hh * NTOK + a1i + 1) * NTOK + (a2i + 1)] = v + mv;
        }
    }
}

// ---------------------------------------------------------------- GEMM: C = A * W^T + bias
// A [M][K] f32, W [Nc][K] f32, bias [Nc] f32, C [M][Nc] f32
#define GBM 128
#define GBN 128
#define GBK 16
__global__ __launch_bounds__(256)
void k_gemm(const float* __restrict__ A, const float* __restrict__ W,
            const float* __restrict__ bias, float* __restrict__ C,
            int M, int Nc, int K)
{
    __shared__ float sA[GBK][GBM + 4];
    __shared__ float sB[GBK][GBN + 4];
    int tid = threadIdx.x;
    int row0 = blockIdx.x * GBM, col0 = blockIdx.y * GBN;
    int tx = tid & 15, ty = tid >> 4;
    float acc[8][8];
#pragma unroll
    for (int i = 0; i < 8; ++i)
#pragma unroll
        for (int j = 0; j < 8; ++j) acc[i][j] = 0.f;

    for (int kb = 0; kb < K; kb += GBK) {
        for (int q = tid; q < 512; q += 256) {
            int r = q >> 2, kk = (q & 3) << 2;
            float4 v = *(const float4*)&A[(size_t)(row0 + r) * K + kb + kk];
            sA[kk + 0][r] = v.x; sA[kk + 1][r] = v.y;
            sA[kk + 2][r] = v.z; sA[kk + 3][r] = v.w;
        }
        for (int q = tid; q < 512; q += 256) {
            int c = q >> 2, kk = (q & 3) << 2;
            float4 v = *(const float4*)&W[(size_t)(col0 + c) * K + kb + kk];
            sB[kk + 0][c] = v.x; sB[kk + 1][c] = v.y;
            sB[kk + 2][c] = v.z; sB[kk + 3][c] = v.w;
        }
        __syncthreads();
#pragma unroll
        for (int k = 0; k < GBK; ++k) {
            float a[8], bv[8];
            *(float4*)&a[0] = *(const float4*)&sA[k][ty * 8];
            *(float4*)&a[4] = *(const float4*)&sA[k][ty * 8 + 4];
            *(float4*)&bv[0] = *(const float4*)&sB[k][tx * 8];
            *(float4*)&bv[4] = *(const float4*)&sB[k][tx * 8 + 4];
#pragma unroll
            for (int i = 0; i < 8; ++i)
#pragma unroll
                for (int j = 0; j < 8; ++j) acc[i][j] += a[i] * bv[j];
        }
        __syncthreads();
    }
    float bv[8];
#pragma unroll
    for (int j = 0; j < 8; ++j) bv[j] = bias[col0 + tx * 8 + j];
#pragma unroll
    for (int i = 0; i < 8; ++i) {
        float* cp = &C[(size_t)(row0 + ty * 8 + i) * Nc + col0 + tx * 8];
#pragma unroll
        for (int j = 0; j < 8; ++j) cp[j] = acc[i][j] + bv[j];
    }
}

// ---------------------------------------------------------------- attention
__global__ __launch_bounds__(256)
void k_attn(const float* __restrict__ qkv,   // [B][65][1536]
            const float* __restrict__ biasb, // [B][16][65][65]
            float* __restrict__ out)         // [B][65][512]
{
    int h = blockIdx.x, b = blockIdx.y;
    int tid = threadIdx.x;
    __shared__ float sq[NTOK * HDD];
    __shared__ float sk[NTOK * HDD];
    __shared__ float svT[HDD][NTOK + 3];   // transposed V
    __shared__ float sS[NTOK][NTOK + 3];   // scores (row stride 68 -> 16B aligned)

    const float* qb = qkv + (size_t)b * NTOK * (3 * DD) + h * HDD;
    for (int i = tid; i < NTOK * HDD; i += 256) {
        int n = i >> 5, d = i & 31;
        const float* row = qb + (size_t)n * (3 * DD);
        sq[i] = row[d];
        sk[i] = row[DD + d];
        svT[d][n] = row[2 * DD + d];
    }
    __syncthreads();

    const float scale = 0.17677669529663687f;   // 1/sqrt(32)
    const float* bp = biasb + (((size_t)b * HH + h) * NTOK) * NTOK;
    for (int e = tid; e < NTOK * NTOK; e += 256) {
        int i = e / NTOK, j = e - i * NTOK;
        const float* qr = &sq[i * HDD];
        const float* kr = &sk[j * HDD];
        float dot = 0.f;
#pragma unroll
        for (int d4 = 0; d4 < HDD; d4 += 4) {
            float4 qv = *(const float4*)&qr[d4];
            float4 kv = *(const float4*)&kr[d4];
            dot += qv.x * kv.x + qv.y * kv.y + qv.z * kv.z + qv.w * kv.w;
        }
        sS[i][j] = dot * scale + bp[i * NTOK + j];
    }
    __syncthreads();

    if (tid < NTOK) {
        float* r = sS[tid];
        float mx = -INFINITY;
        for (int j = 0; j < NTOK; ++j) mx = fmaxf(mx, r[j]);
        float s = 0.f;
        for (int j = 0; j < NTOK; ++j) { float p = expf(r[j] - mx); r[j] = p; s += p; }
        float inv = 1.f / s;
        for (int j = 0; j < NTOK; ++j) r[j] *= inv;
    }
    __syncthreads();

    float* ob = out + (size_t)b * NTOK * DD + h * HDD;
    for (int e = tid; e < NTOK * HDD; e += 256) {
        int n = e >> 5, d = e & 31;
        const float* pr = sS[n];
        const float* vr = &svT[d][0];
        float accv = 0.f;
#pragma unroll
        for (int j4 = 0; j4 < 64; j4 += 4) {
            float4 pv = *(const float4*)&pr[j4];
            float4 vv = *(const float4*)&vr[j4];
            accv += pv.x * vv.x + pv.y * vv.y + pv.z * vv.z + pv.w * vv.w;
        }
        accv += pr[64] * vr[64];
        ob[(size_t)n * DD + d] = accv;
    }
}

// ---------------------------------------------------------------- launch
extern "C" void kernel_launch(void* const* d_in, const int* in_sizes, int n_in,
                              void* d_out, int out_size, void* d_ws, size_t ws_size,
                              hipStream_t stream)
{
    (void)in_sizes; (void)n_in; (void)out_size; (void)ws_size;
    const int*   atom_fea    = (const int*)d_in[0];
    const int*   bond_adj    = (const int*)d_in[1];
    const float* dist_adj    = (const float*)d_in[2];
    const float* atom_tables = (const float*)d_in[3];
    const float* ga_means    = (const float*)d_in[4];
    const float* ga_stds     = (const float*)d_in[5];
    const float* ga_mul      = (const float*)d_in[6];
    const float* ga_bias     = (const float*)d_in[7];
    const float* graph_token = (const float*)d_in[8];
    const float* edge_tables = (const float*)d_in[9];
    const float* gb_means    = (const float*)d_in[10];
    const float* gb_stds     = (const float*)d_in[11];
    const float* gb_mul      = (const float*)d_in[12];
    const float* gb_bias     = (const float*)d_in[13];
    const float* egt         = (const float*)d_in[14];
    const float* in_proj_w   = (const float*)d_in[15];
    const float* in_proj_b   = (const float*)d_in[16];
    const float* out_proj_w  = (const float*)d_in[17];
    const float* out_proj_b  = (const float*)d_in[18];

    float* xbuf = (float*)d_ws;                               // [B][65][512]   34.1 MB
    float* qkv  = xbuf + (size_t)BB * NTOK * DD;              // [B][65][1536] 102.2 MB
    float* biasb = qkv + (size_t)BB * NTOK * 3 * DD;          // [B][16][65][65] 69.2 MB

    k_atom_embed<<<dim3(NTOK, BB), 256, 0, stream>>>(atom_fea, atom_tables, ga_means,
                                                     ga_stds, ga_mul, ga_bias, graph_token, xbuf);
    k_edge_bias<<<dim3(BB), 1024, 0, stream>>>(bond_adj, dist_adj, edge_tables, gb_means,
                                               gb_stds, gb_mul, gb_bias, egt, biasb);
    k_gemm<<<dim3(130, 12), 256, 0, stream>>>(xbuf, in_proj_w, in_proj_b, qkv,
                                              BB * NTOK, 3 * DD, DD);
    k_attn<<<dim3(HH, BB), 256, 0, stream>>>(qkv, biasb, xbuf);
    k_gemm<<<dim3(130, 4), 256, 0, stream>>>(xbuf, out_proj_w, out_proj_b, (float*)d_out,
                                             BB * NTOK, DD, DD);
}

// Round 4
// 551.548 us; speedup vs baseline: 2.4321x; 1.6718x over previous
//
#include <hip/hip_runtime.h>
#include <math.h>

#define BB 256
#define NAA 64
#define NTOK 65
#define DD 512
#define KK2 1024          // split-A doubled K
#define HH 16
#define HDD 32
#define NGEFF 4           // bond values 0..15 -> bits 4,5 of (bond-1) always 0; table row 0 is 0
#define MAXP 50

typedef short bf16x8 __attribute__((ext_vector_type(8)));
typedef float f32x4 __attribute__((ext_vector_type(4)));

static __device__ __forceinline__ unsigned short f2b_rne(float f) {
    unsigned u = __float_as_uint(f);
    unsigned r = (u + 0x7FFFu + ((u >> 16) & 1u)) >> 16;
    return (unsigned short)r;
}
static __device__ __forceinline__ float b2f(unsigned short u) {
    return __uint_as_float(((unsigned)u) << 16);
}
static __device__ __forceinline__ void gload16(const void* g, void* l) {
    __builtin_amdgcn_global_load_lds(
        (const __attribute__((address_space(1))) unsigned int*)g,
        (__attribute__((address_space(3))) unsigned int*)l, 16, 0, 0);
}

// ---------------------------------------------------------------- weight convert+duplicate
// w2[row][k] = w2[row][k+512] = bf16(w[row][k]);  rows of length 1024
__global__ __launch_bounds__(256)
void k_cvt_wdup(const float* __restrict__ w, unsigned short* __restrict__ w2, int n)
{
    int i = blockIdx.x * 256 + threadIdx.x;
    if (i >= n) return;
    int row = i >> 9, k = i & 511;
    unsigned short v = f2b_rne(w[i]);
    w2[(size_t)row * KK2 + k] = v;
    w2[(size_t)row * KK2 + k + 512] = v;
}

// ---------------------------------------------------------------- atom embed -> split bf16
__global__ __launch_bounds__(256)
void k_atom_embed(const int* __restrict__ atom_fea,          // [B][7][64]
                  const float* __restrict__ atom_tables,     // [6][100][512]
                  const float* __restrict__ ga_means,        // [512]
                  const float* __restrict__ ga_stds,
                  const float* __restrict__ ga_mul,
                  const float* __restrict__ ga_bias,
                  const float* __restrict__ graph_token,     // [512]
                  unsigned short* __restrict__ x2)           // [B*65][1024] hi|lo
{
    int n = blockIdx.x;   // 0..64
    int b = blockIdx.y;
    int tid = threadIdx.x;
    unsigned short* xp = x2 + ((size_t)b * NTOK + n) * KK2;
    if (n == 0) {
        for (int d = tid; d < DD; d += 256) {
            float val = graph_token[d];
            unsigned short h = f2b_rne(val);
            xp[d] = h;
            xp[d + 512] = f2b_rne(val - b2f(h));
        }
        return;
    }
    int a = n - 1;
    int fea[6];
#pragma unroll
    for (int i = 0; i < 6; ++i) fea[i] = atom_fea[((b * 7) + i) * NAA + a];
    int ci = atom_fea[((b * 7) + 6) * NAA + a];
    float cont = (float)ci;
    float g = ga_mul[0] * cont + ga_bias[0];
    const float Ac = 2.5066268f;    // sqrt(2*3.14159)
    for (int d = tid; d < DD; d += 256) {
        float val = 0.f;
        if (ci != 0) {
            float sd = fabsf(ga_stds[d]) + 1e-5f;
            float t = (g - ga_means[d]) / sd;
            val = expf(-0.5f * t * t) / (Ac * sd);
        }
#pragma unroll
        for (int i = 0; i < 6; ++i)
            val += atom_tables[((i * 100) + fea[i]) * DD + d];
        unsigned short h = f2b_rne(val);
        xp[d] = h;
        xp[d + 512] = f2b_rne(val - b2f(h));
    }
}

// ---------------------------------------------------------------- edge bias (fully LDS-resident)
__global__ __launch_bounds__(1024)
void k_edge_bias(const int* __restrict__ bond_adj,           // [B][64][64]
                 const float* __restrict__ dist_adj,         // [B][64][64]
                 const float* __restrict__ edge_tables,      // [6][51][16]
                 const float* __restrict__ gb_means,         // [16]
                 const float* __restrict__ gb_stds,
                 const float* __restrict__ gb_mul,
                 const float* __restrict__ gb_bias,
                 const float* __restrict__ egt,              // [16]
                 float* __restrict__ biasb)                  // [B][16][65][65]
{
    int b = blockIdx.x;
    int tid = threadIdx.x;
    __shared__ float s_j[64 * 65];
    __shared__ float s_jn[64 * 65];
    __shared__ unsigned long long s_brow[64];
    __shared__ unsigned char s_idx[16][4096];      // [t*4+hop][p]
    __shared__ float s_et[4][51][17];
    __shared__ int s_bond[4096];
    __shared__ float s_gmn[16], s_gis[16], s_gcf[16], s_egt[16];

    const int* badj = bond_adj + (size_t)b * 4096;
    const float Ac = 2.5066268f;

    for (int q = tid; q < 4096; q += 1024) s_bond[q] = badj[q];
    for (int q = tid; q < 4 * 51 * 16; q += 1024) {
        int t = q >> 4;
        int hh = q & 15;
        s_et[t / 51][t % 51][hh] = edge_tables[q];
    }
    if (tid < 16) {
        float sd = fabsf(gb_stds[tid]) + 1e-5f;
        s_gmn[tid] = gb_means[tid];
        s_gis[tid] = 1.f / sd;
        s_gcf[tid] = 1.f / (Ac * sd);
        s_egt[tid] = egt[tid];
    }
    __syncthreads();

    for (int t = 0; t < NGEFF; ++t) {
        for (int q = tid; q < 4096; q += 1024) {
            int bd = s_bond[q];
            int bit = (bd > 0) ? ((bd - 1) >> t) & 1 : 0;
            unsigned long long m = __ballot(bit != 0);
            if ((q & 63) == 0) s_brow[q >> 6] = m;
            s_j[(q >> 6) * 65 + (q & 63)] = (float)bit;
            s_idx[t * 4][q] = (unsigned char)bit;
        }
        __syncthreads();
        float* cur = s_j;
        float* nxt = s_jn;
        for (int hop = 1; hop < 4; ++hop) {
            int r = tid >> 4;
            int c0 = (tid & 15) << 2;
            float a0 = 0.f, a1 = 0.f, a2 = 0.f, a3 = 0.f;
            for (int k = 0; k < 64; ++k) {
                float jv = cur[r * 65 + k];
                unsigned int rs = (unsigned int)(s_brow[k] >> c0);
                a0 += (rs & 1u) ? jv : 0.f;
                a1 += (rs & 2u) ? jv : 0.f;
                a2 += (rs & 4u) ? jv : 0.f;
                a3 += (rs & 8u) ? jv : 0.f;
            }
            nxt[r * 65 + c0 + 0] = a0;
            nxt[r * 65 + c0 + 1] = a1;
            nxt[r * 65 + c0 + 2] = a2;
            nxt[r * 65 + c0 + 3] = a3;
            int p0 = r * 64 + c0;
            int i0 = (int)a0; if (i0 > MAXP) i0 = MAXP;
            int i1 = (int)a1; if (i1 > MAXP) i1 = MAXP;
            int i2 = (int)a2; if (i2 > MAXP) i2 = MAXP;
            int i3 = (int)a3; if (i3 > MAXP) i3 = MAXP;
            s_idx[t * 4 + hop][p0 + 0] = (unsigned char)i0;
            s_idx[t * 4 + hop][p0 + 1] = (unsigned char)i1;
            s_idx[t * 4 + hop][p0 + 2] = (unsigned char)i2;
            s_idx[t * 4 + hop][p0 + 3] = (unsigned char)i3;
            __syncthreads();
            float* tmp = cur; cur = nxt; nxt = tmp;
        }
    }

    float* bb = biasb + (size_t)b * HH * NTOK * NTOK;
    for (int i = tid; i < HH * NTOK; i += 1024) {
        int hh = i / NTOK, j = i - hh * NTOK;
        float e = s_egt[hh];
        bb[(hh * NTOK + 0) * NTOK + j] = e;
        bb[(hh * NTOK + j) * NTOK + 0] = e;
    }
    float gm = gb_mul[0], gbi = gb_bias[0];
    for (int p = tid; p < 4096; p += 1024) {
        int a1i = p >> 6, a2i = p & 63;
        float dist = dist_adj[(size_t)b * 4096 + p];
        float g = gm * dist + gbi;
        float mv = (s_bond[p] != 0) ? 0.f : -INFINITY;
        int ixs[16];
#pragma unroll
        for (int q = 0; q < 16; ++q) ixs[q] = s_idx[q][p];
#pragma unroll
        for (int hh = 0; hh < 16; ++hh) {
            float v = 0.f;
            if (dist != 0.f) {
                float tt = (g - s_gmn[hh]) * s_gis[hh];
                v = expf(-0.5f * tt * tt) * s_gcf[hh];
            }
#pragma unroll
            for (int q = 0; q < 16; ++q) v += s_et[q >> 2][ixs[q]][hh];
            bb[(hh * NTOK + a1i + 1) * NTOK + (a2i + 1)] = v + mv;
        }
    }
}

// ---------------------------------------------------------------- MFMA GEMM
// C[M][N] f32 = A[M][KK] bf16 . W[N][KK] bf16 (B^T layout) + bias[N] f32
// 128x128 tile, BK=32, 4 waves (2x2), 16x16x32 MFMA, global_load_lds staging.
#define TM 128
#define TN 128
#define TBK 32
__global__ __launch_bounds__(256)
void k_gemm_mfma(const unsigned short* __restrict__ A,
                 const unsigned short* __restrict__ W,
                 const float* __restrict__ bias,
                 float* __restrict__ C,
                 int M, int N, int KK)
{
    __shared__ short sA[TM * TBK];   // 8 KB
    __shared__ short sB[TN * TBK];   // 8 KB
    int tid = threadIdx.x;
    int lane = tid & 63, w = tid >> 6;
    int wm = w >> 1, wn = w & 1;
    int row0 = blockIdx.x * TM, col0 = blockIdx.y * TN;

    f32x4 zf = {0.f, 0.f, 0.f, 0.f};
    f32x4 acc[4][4];
#pragma unroll
    for (int m = 0; m < 4; ++m)
#pragma unroll
        for (int n = 0; n < 4; ++n) acc[m][n] = zf;

    int srow = tid >> 2;
    int skoff = (tid & 3) << 3;
    const unsigned short* gA0 = A + (size_t)(row0 + srow) * KK + skoff;
    const unsigned short* gA1 = A + (size_t)(row0 + srow + 64) * KK + skoff;
    const unsigned short* gB0 = W + (size_t)(col0 + srow) * KK + skoff;
    const unsigned short* gB1 = W + (size_t)(col0 + srow + 64) * KK + skoff;
    short* lA0 = sA + tid * 8;
    short* lA1 = sA + 2048 + tid * 8;
    short* lB0 = sB + tid * 8;
    short* lB1 = sB + 2048 + tid * 8;

    int fk = (lane >> 4) << 3;    // k-chunk 0,8,16,24
    int fr = lane & 15;           // row/col within fragment

    for (int kb = 0; kb < KK; kb += TBK) {
        gload16(gA0 + kb, lA0);
        gload16(gA1 + kb, lA1);
        gload16(gB0 + kb, lB0);
        gload16(gB1 + kb, lB1);
        __syncthreads();           // drains vmcnt (global_load_lds) + lgkmcnt
        bf16x8 af[4], bg[4];
#pragma unroll
        for (int m = 0; m < 4; ++m)
            af[m] = *(const bf16x8*)&sA[(wm * 64 + m * 16 + fr) * TBK + fk];
#pragma unroll
        for (int n = 0; n < 4; ++n)
            bg[n] = *(const bf16x8*)&sB[(wn * 64 + n * 16 + fr) * TBK + fk];
#pragma unroll
        for (int m = 0; m < 4; ++m)
#pragma unroll
            for (int n = 0; n < 4; ++n)
                acc[m][n] = __builtin_amdgcn_mfma_f32_16x16x32_bf16(af[m], bg[n], acc[m][n], 0, 0, 0);
        __syncthreads();
    }

    int crg = (lane >> 4) << 2;   // C row group: row=(lane>>4)*4+reg, col=lane&15
#pragma unroll
    for (int m = 0; m < 4; ++m) {
#pragma unroll
        for (int n = 0; n < 4; ++n) {
            int col = col0 + wn * 64 + n * 16 + fr;
            float bv = bias[col];
            int rowb = row0 + wm * 64 + m * 16 + crg;
#pragma unroll
            for (int r = 0; r < 4; ++r)
                C[(size_t)(rowb + r) * N + col] = acc[m][n][r] + bv;
        }
    }
}

// ---------------------------------------------------------------- attention -> split bf16 out
__global__ __launch_bounds__(256)
void k_attn(const float* __restrict__ qkv,   // [B][65][1536]
            const float* __restrict__ biasb, // [B][16][65][65]
            unsigned short* __restrict__ o2) // [B*65][1024] hi|lo
{
    int h = blockIdx.x, b = blockIdx.y;
    int tid = threadIdx.x;
    __shared__ float sq[NTOK * HDD];
    __shared__ float sk[NTOK * HDD];
    __shared__ float svT[HDD][NTOK + 3];
    __shared__ float sS[NTOK][NTOK + 3];

    const float* qb = qkv + (size_t)b * NTOK * (3 * DD) + h * HDD;
    for (int i = tid; i < NTOK * HDD; i += 256) {
        int n = i >> 5, d = i & 31;
        const float* row = qb + (size_t)n * (3 * DD);
        sq[i] = row[d];
        sk[i] = row[DD + d];
        svT[d][n] = row[2 * DD + d];
    }
    __syncthreads();

    const float scale = 0.17677669529663687f;   // 1/sqrt(32)
    const float* bp = biasb + (((size_t)b * HH + h) * NTOK) * NTOK;
    for (int e = tid; e < NTOK * NTOK; e += 256) {
        int i = e / NTOK, j = e - i * NTOK;
        const float* qr = &sq[i * HDD];
        const float* kr = &sk[j * HDD];
        float dot = 0.f;
#pragma unroll
        for (int d4 = 0; d4 < HDD; d4 += 4) {
            float4 qv = *(const float4*)&qr[d4];
            float4 kv = *(const float4*)&kr[d4];
            dot += qv.x * kv.x + qv.y * kv.y + qv.z * kv.z + qv.w * kv.w;
        }
        sS[i][j] = dot * scale + bp[i * NTOK + j];
    }
    __syncthreads();

    if (tid < NTOK) {
        float* r = sS[tid];
        float mx = -INFINITY;
        for (int j = 0; j < NTOK; ++j) mx = fmaxf(mx, r[j]);
        float s = 0.f;
        for (int j = 0; j < NTOK; ++j) { float p = expf(r[j] - mx); r[j] = p; s += p; }
        float inv = 1.f / s;
        for (int j = 0; j < NTOK; ++j) r[j] *= inv;
    }
    __syncthreads();

    unsigned short* ob = o2 + (size_t)b * NTOK * KK2 + h * HDD;
    for (int e = tid; e < NTOK * HDD; e += 256) {
        int n = e >> 5, d = e & 31;
        const float* pr = sS[n];
        const float* vr = &svT[d][0];
        float accv = 0.f;
#pragma unroll
        for (int j4 = 0; j4 < 64; j4 += 4) {
            float4 pv = *(const float4*)&pr[j4];
            float4 vv = *(const float4*)&vr[j4];
            accv += pv.x * vv.x + pv.y * vv.y + pv.z * vv.z + pv.w * vv.w;
        }
        accv += pr[64] * vr[64];
        unsigned short hi = f2b_rne(accv);
        ob[(size_t)n * KK2 + d] = hi;
        ob[(size_t)n * KK2 + 512 + d] = f2b_rne(accv - b2f(hi));
    }
}

// ---------------------------------------------------------------- launch
extern "C" void kernel_launch(void* const* d_in, const int* in_sizes, int n_in,
                              void* d_out, int out_size, void* d_ws, size_t ws_size,
                              hipStream_t stream)
{
    (void)in_sizes; (void)n_in; (void)out_size; (void)ws_size;
    const int*   atom_fea    = (const int*)d_in[0];
    const int*   bond_adj    = (const int*)d_in[1];
    const float* dist_adj    = (const float*)d_in[2];
    const float* atom_tables = (const float*)d_in[3];
    const float* ga_means    = (const float*)d_in[4];
    const float* ga_stds     = (const float*)d_in[5];
    const float* ga_mul      = (const float*)d_in[6];
    const float* ga_bias     = (const float*)d_in[7];
    const float* graph_token = (const float*)d_in[8];
    const float* edge_tables = (const float*)d_in[9];
    const float* gb_means    = (const float*)d_in[10];
    const float* gb_stds     = (const float*)d_in[11];
    const float* gb_mul      = (const float*)d_in[12];
    const float* gb_bias     = (const float*)d_in[13];
    const float* egt         = (const float*)d_in[14];
    const float* in_proj_w   = (const float*)d_in[15];
    const float* in_proj_b   = (const float*)d_in[16];
    const float* out_proj_w  = (const float*)d_in[17];
    const float* out_proj_b  = (const float*)d_in[18];

    const size_t MROWS = (size_t)BB * NTOK;                   // 16640
    char* base = (char*)d_ws;
    unsigned short* x2  = (unsigned short*)base;              // 34.1 MB [16640][1024] (reused as o2)
    float* qkv   = (float*)(base + MROWS * KK2 * 2);          // 102.2 MB [16640][1536]
    float* biasb = (float*)(base + MROWS * KK2 * 2 + MROWS * 3 * DD * 4);      // 69.2 MB
    unsigned short* wq2 = (unsigned short*)((char*)biasb + (size_t)BB * HH * NTOK * NTOK * 4); // 3.1 MB
    unsigned short* wo2 = wq2 + (size_t)3 * DD * KK2;         // 1.05 MB

    k_cvt_wdup<<<dim3((3 * DD * DD + 255) / 256), 256, 0, stream>>>(in_proj_w, wq2, 3 * DD * DD);
    k_cvt_wdup<<<dim3((DD * DD + 255) / 256), 256, 0, stream>>>(out_proj_w, wo2, DD * DD);
    k_atom_embed<<<dim3(NTOK, BB), 256, 0, stream>>>(atom_fea, atom_tables, ga_means,
                                                     ga_stds, ga_mul, ga_bias, graph_token, x2);
    k_edge_bias<<<dim3(BB), 1024, 0, stream>>>(bond_adj, dist_adj, edge_tables, gb_means,
                                               gb_stds, gb_mul, gb_bias, egt, biasb);
    k_gemm_mfma<<<dim3(130, 12), 256, 0, stream>>>(x2, wq2, in_proj_b, qkv,
                                                   (int)MROWS, 3 * DD, KK2);
    k_attn<<<dim3(HH, BB), 256, 0, stream>>>(qkv, biasb, x2 /* reused as o2 */);
    k_gemm_mfma<<<dim3(130, 4), 256, 0, stream>>>(x2, wo2, out_proj_b, (float*)d_out,
                                                  (int)MROWS, DD, KK2);
}